// Round 3
// baseline (113.221 us; speedup 1.0000x reference)
//
#include <hip/hip_runtime.h>

typedef float f32x2 __attribute__((ext_vector_type(2)));

#define BLOCK 256
#define P 4              // A-points per thread
#define SUB 64           // B points staged per round per wave
#define NWAVE 4          // j-slice split across the block's waves

// LDS layout per j-pair record (32B): {x0,x1,y0,y1} {z0,z1,h0,h1}
// -> two broadcast ds_read_b128 per record, f32x2 operands are subpairs.

__global__ __launch_bounds__(256) void chamfer_kernel(
    const float* __restrict__ points,   // [BS][N][3]
    const float* __restrict__ gts,      // [BS][N][3]
    float* __restrict__ sums,           // [2]
    int N)
{
    const int b   = blockIdx.y;
    const int dir = blockIdx.z;
    const float* A = dir ? gts    : points;
    const float* B = dir ? points : gts;

    const int w = threadIdx.x >> 6;
    const int l = threadIdx.x & 63;

    const float* Ab = A + (size_t)b * N * 3;
    const float* Bb = B + (size_t)b * N * 3;

    const int pbase = blockIdx.x * BLOCK;

    // Pre-negated, half-duplicated A operands (loop-invariant).
    f32x2 nax[P], nay[P], naz[P], hap[P];
    float mind[P];
    #pragma unroll
    for (int p = 0; p < P; ++p) {
        const int i = pbase + p * 64 + l;
        const float ax = Ab[i * 3 + 0];
        const float ay = Ab[i * 3 + 1];
        const float az = Ab[i * 3 + 2];
        const float ha = 0.5f * (ax * ax + ay * ay + az * az);
        nax[p] = (f32x2){-ax, -ax};
        nay[p] = (f32x2){-ay, -ay};
        naz[p] = (f32x2){-az, -az};
        hap[p] = (f32x2){ha, ha};
        mind[p] = 3.4e38f;
    }

    __shared__ float4 tile[NWAVE][SUB];     // 2 float4 per j-pair record
    __shared__ float  pmin[NWAVE][BLOCK];

    const int slice = N / NWAVE;            // 1024
    const int jbase = w * slice;

    // prefetch round 0's B point
    int j = jbase + l;
    float bx = Bb[j * 3 + 0];
    float by = Bb[j * 3 + 1];
    float bz = Bb[j * 3 + 2];

    for (int r = 0; r < slice; r += SUB) {
        const float hb = 0.5f * (bx * bx + by * by + bz * bz);
        __syncthreads();   // previous round's reads complete
        {
            // j-pair transposed record write (4x ds_write_b32)
            float* f = (float*)&tile[w][(l >> 1) * 2];
            const int half = l & 1;
            f[half + 0] = bx;
            f[half + 2] = by;
            f[half + 4] = bz;
            f[half + 6] = hb;
        }
        // issue next round's global loads now; latency hides under inner loop
        if (r + SUB < slice) {
            j = jbase + r + SUB + l;
            bx = Bb[j * 3 + 0];
            by = Bb[j * 3 + 1];
            bz = Bb[j * 3 + 2];
        }
        __syncthreads();   // records visible

        #pragma unroll 8
        for (int jp = 0; jp < SUB / 2; ++jp) {
            const float4 xy = tile[w][jp * 2 + 0];   // {x0,x1,y0,y1}
            const float4 zh = tile[w][jp * 2 + 1];   // {z0,z1,h0,h1}
            const f32x2 gx = {xy.x, xy.y};
            const f32x2 gy = {xy.z, xy.w};
            const f32x2 gz = {zh.x, zh.y};
            const f32x2 gh = {zh.z, zh.w};
            #pragma unroll
            for (int p = 0; p < P; ++p) {
                f32x2 t;
                asm("v_pk_fma_f32 %0, %1, %2, %3"
                    : "=v"(t) : "v"(nax[p]), "v"(gx), "v"(hap[p]));
                asm("v_pk_fma_f32 %0, %1, %2, %0"
                    : "+v"(t) : "v"(nay[p]), "v"(gy));
                asm("v_pk_fma_f32 %0, %1, %2, %0"
                    : "+v"(t) : "v"(naz[p]), "v"(gz));
                f32x2 q;   // q = hb + (ha - a.b) = d^2/2
                asm("v_pk_add_f32 %0, %1, %2"
                    : "=v"(q) : "v"(gh), "v"(t));
                asm("v_min3_f32 %0, %0, %1, %2"
                    : "+v"(mind[p]) : "v"(q.x), "v"(q.y));
            }
        }
    }

    // combine the 4 waves' partial mins (each scanned a different j-slice)
    #pragma unroll
    for (int p = 0; p < P; ++p)
        pmin[w][p * 64 + l] = mind[p];
    __syncthreads();

    const int t = threadIdx.x;
    const float q = fminf(fminf(pmin[0][t], pmin[1][t]),
                          fminf(pmin[2][t], pmin[3][t]));
    float v = sqrtf(fmaxf(q + q, 0.0f));   // d = sqrt(2q)

    for (int off = 32; off > 0; off >>= 1)
        v += __shfl_down(v, off);

    __shared__ float wsum[NWAVE];
    if (l == 0) wsum[w] = v;
    __syncthreads();
    if (t == 0)
        atomicAdd(sums + dir, wsum[0] + wsum[1] + wsum[2] + wsum[3]);
}

__global__ void chamfer_finalize_kernel(const float* __restrict__ sums,
                                        float* __restrict__ out,
                                        float scale)
{
    const float p2g = sums[0] * scale;
    const float g2p = sums[1] * scale;
    out[0] = p2g + g2p;
    out[1] = p2g;
    out[2] = g2p;
}

extern "C" void kernel_launch(void* const* d_in, const int* in_sizes, int n_in,
                              void* d_out, int out_size, void* d_ws, size_t ws_size,
                              hipStream_t stream) {
    const float* points = (const float*)d_in[0];
    const float* gts    = (const float*)d_in[1];
    float* out = (float*)d_out;
    float* ws  = (float*)d_ws;

    const int BS = 32, N = 4096;

    hipMemsetAsync(d_ws, 0, 2 * sizeof(float), stream);

    dim3 grid(N / BLOCK, BS, 2);
    chamfer_kernel<<<grid, BLOCK, 0, stream>>>(points, gts, ws, N);

    const float scale = 1.0f / (float)(BS * N);
    chamfer_finalize_kernel<<<1, 1, 0, stream>>>(ws, out, scale);
}